// Round 1
// baseline (21055.138 us; speedup 1.0000x reference)
//
#include <hip/hip_runtime.h>
#include <math.h>

// Problem constants
#define SEQ 2048
#define EMB_D 512
#define HID 512
#define NTAGS 12
#define START_TAG 10
#define STOP_TAG 11
#define NEGV (-10000.0f)

__device__ __forceinline__ float sigf(float x) { return 1.0f / (1.0f + expf(-x)); }

// ---------------------------------------------------------------------------
// K0: embedding gather  x0[t][e] = emb[sentence[t]][e]
// ---------------------------------------------------------------------------
__global__ void k_embed(const int* __restrict__ sent, const float* __restrict__ emb,
                        float* __restrict__ x0) {
    int t = blockIdx.x;
    int tid = threadIdx.x;  // 128 threads, 128 float4 = 512 floats
    int row = sent[t];
    const float4* src = (const float4*)(emb + (size_t)row * EMB_D);
    float4* dst = (float4*)(x0 + (size_t)t * EMB_D);
    dst[tid] = src[tid];
}

// ---------------------------------------------------------------------------
// K1/K3: fp32 GEMM  C[d][m][n] = sum_k A[m][k] * B[d][n][k] + biasA[d][n]+biasB[d][n]
// A[m][k] = (k<512 ? Af[m*512+k] : Ab[m*512+(k-512)])  (handles concat input)
// M = N = 2048 fixed, K in {512,1024}. Tile 64x64, BK=32, 256 threads, 4x4/thread.
// ---------------------------------------------------------------------------
#define BM 64
#define BN 64
#define BKT 32
#define LDT 68

__global__ __launch_bounds__(256) void k_gemm(
    const float* __restrict__ Af, const float* __restrict__ Ab,
    const float* __restrict__ B,
    const float* __restrict__ biasA, const float* __restrict__ biasB,
    float* __restrict__ C, int K) {
    const int N = 2048;
    int dir = blockIdx.z;
    const float* Bd = B + (size_t)dir * N * K;
    const float* bA = biasA + dir * N;
    const float* bB = biasB + dir * N;
    float* Cd = C + (size_t)dir * 2048 * N;
    int m0 = blockIdx.y * BM, n0 = blockIdx.x * BN;

    __shared__ float As[BKT * LDT];
    __shared__ float Bs[BKT * LDT];

    int tid = threadIdx.x;
    int lrow = tid >> 2;          // 0..63
    int lk4 = (tid & 3) * 8;      // 0,8,16,24
    int tx = tid & 15, ty = tid >> 4;

    float acc[4][4] = {};

    for (int kt = 0; kt < K; kt += BKT) {
        // load A tile (k-major in LDS)
        {
            int m = m0 + lrow;
#pragma unroll
            for (int hh = 0; hh < 2; ++hh) {
                int k = kt + lk4 + hh * 4;
                const float* src = (k < 512) ? (Af + (size_t)m * 512 + k)
                                             : (Ab + (size_t)m * 512 + (k - 512));
                float4 v = *(const float4*)src;
                int kl = lk4 + hh * 4;
                As[(kl + 0) * LDT + lrow] = v.x;
                As[(kl + 1) * LDT + lrow] = v.y;
                As[(kl + 2) * LDT + lrow] = v.z;
                As[(kl + 3) * LDT + lrow] = v.w;
            }
        }
        // load B tile
        {
            int n = n0 + lrow;
#pragma unroll
            for (int hh = 0; hh < 2; ++hh) {
                int k = kt + lk4 + hh * 4;
                float4 v = *(const float4*)(Bd + (size_t)n * K + k);
                int kl = lk4 + hh * 4;
                Bs[(kl + 0) * LDT + lrow] = v.x;
                Bs[(kl + 1) * LDT + lrow] = v.y;
                Bs[(kl + 2) * LDT + lrow] = v.z;
                Bs[(kl + 3) * LDT + lrow] = v.w;
            }
        }
        __syncthreads();
#pragma unroll
        for (int kk = 0; kk < BKT; ++kk) {
            float4 av = *(const float4*)&As[kk * LDT + ty * 4];
            float4 bv = *(const float4*)&Bs[kk * LDT + tx * 4];
            acc[0][0] += av.x * bv.x; acc[0][1] += av.x * bv.y; acc[0][2] += av.x * bv.z; acc[0][3] += av.x * bv.w;
            acc[1][0] += av.y * bv.x; acc[1][1] += av.y * bv.y; acc[1][2] += av.y * bv.z; acc[1][3] += av.y * bv.w;
            acc[2][0] += av.z * bv.x; acc[2][1] += av.z * bv.y; acc[2][2] += av.z * bv.z; acc[2][3] += av.z * bv.w;
            acc[3][0] += av.w * bv.x; acc[3][1] += av.w * bv.y; acc[3][2] += av.w * bv.z; acc[3][3] += av.w * bv.w;
        }
        __syncthreads();
    }
#pragma unroll
    for (int i = 0; i < 4; ++i) {
        int m = m0 + ty * 4 + i;
#pragma unroll
        for (int j = 0; j < 4; ++j) {
            int n = n0 + tx * 4 + j;
            Cd[(size_t)m * N + n] = acc[i][j] + bA[n] + bB[n];
        }
    }
}

// ---------------------------------------------------------------------------
// K2/K4: LSTM recurrence, one layer, both directions.
// 64 WGs (32 per direction), 256 threads each, persistent over 2048 steps.
// Each WG owns 16 hidden units (64 gate rows), Whh slice in registers
// (128 floats/thread). Cross-WG h broadcast via global + arrival counters.
// ---------------------------------------------------------------------------
__global__ __launch_bounds__(256) void k_lstm(
    const float* __restrict__ Whh,  // [2][2048][512]
    const float* __restrict__ Gi,   // [2][2048][2048]  (Wih@x + bih + bhh)
    float* __restrict__ hstore,     // [2][2048][512]
    int* arrive)                    // [2][2048], pre-zeroed
{
    const int WGS_PER_DIR = 32;
    int wg = blockIdx.x;
    int dir = wg / WGS_PER_DIR;
    int slice = wg % WGS_PER_DIR;
    int u_base = slice * 16;
    int tid = threadIdx.x;

    const float* Whh_d = Whh + (size_t)dir * 2048 * 512;
    const float* Gi_d = Gi + (size_t)dir * 2048 * 2048;
    float* h_d = hstore + (size_t)dir * 2048 * 512;
    int* arr = arrive + dir * 2048;

    int rl = tid >> 2;  // local gate row 0..63
    int kp = tid & 3;   // k-quarter
    int uu = rl >> 2;   // unit offset 0..15
    int gg = rl & 3;    // gate (i,f,g,o)
    int r = gg * 512 + u_base + uu;  // global gate-row in [0,2048)

    // weights into registers: w[j] = Whh[dir][r][kp*128 + j]
    float w[128];
    {
        const float* wsrc = Whh_d + (size_t)r * 512 + kp * 128;
#pragma unroll
        for (int j = 0; j < 128; j += 4) {
            float4 v = *(const float4*)(wsrc + j);
            w[j] = v.x; w[j + 1] = v.y; w[j + 2] = v.z; w[j + 3] = v.w;
        }
    }

    __shared__ __align__(16) float hlds[512];
    __shared__ float gdot[64];
    float c_reg = 0.0f;

    for (int it = 0; it < 2048; ++it) {
        int t = dir ? (2047 - it) : it;
        if (it == 0) {
            if (tid < 128) ((float4*)hlds)[tid] = make_float4(0.f, 0.f, 0.f, 0.f);
        } else {
            if (tid == 0) {
                while (__hip_atomic_load(arr + (it - 1), __ATOMIC_ACQUIRE,
                                         __HIP_MEMORY_SCOPE_AGENT) < WGS_PER_DIR) {
                    __builtin_amdgcn_s_sleep(1);
                }
                __threadfence();  // make peers' h stores visible to whole WG
            }
            __syncthreads();
            int tprev = dir ? (t + 1) : (t - 1);
            if (tid < 128)
                ((float4*)hlds)[tid] = ((const float4*)(h_d + (size_t)tprev * 512))[tid];
        }
        __syncthreads();

        // input-gate term (precomputed), one lane per row
        float gi = 0.f;
        if (kp == 0) gi = Gi_d[(size_t)t * 2048 + r];

        // partial dot over this thread's k-quarter
        float p = 0.f;
        const float4* h4 = (const float4*)hlds + kp * 32;
#pragma unroll
        for (int j4 = 0; j4 < 32; ++j4) {
            float4 hv = h4[j4];
            p += w[4 * j4 + 0] * hv.x;
            p += w[4 * j4 + 1] * hv.y;
            p += w[4 * j4 + 2] * hv.z;
            p += w[4 * j4 + 3] * hv.w;
        }
        p += __shfl_xor(p, 1);
        p += __shfl_xor(p, 2);
        if (kp == 0) gdot[rl] = p + gi;
        __syncthreads();

        if (tid < 16) {
            float iv = gdot[tid * 4 + 0];
            float fv = gdot[tid * 4 + 1];
            float gv = gdot[tid * 4 + 2];
            float ov = gdot[tid * 4 + 3];
            float c = sigf(fv) * c_reg + sigf(iv) * tanhf(gv);
            float h = sigf(ov) * tanhf(c);
            c_reg = c;
            h_d[(size_t)t * 512 + u_base + tid] = h;
            __threadfence();  // device-scope: publish before arrival
        }
        __syncthreads();
        if (tid == 0) {
            __hip_atomic_fetch_add(arr + it, 1, __ATOMIC_RELEASE, __HIP_MEMORY_SCOPE_AGENT);
        }
    }
}

// ---------------------------------------------------------------------------
// K5: feats[t][tag] = sum_k concat(h1f[t],h1b[t])[k] * W_tag[tag][k] + b_tag[tag]
// one 64-thread block per t
// ---------------------------------------------------------------------------
__global__ __launch_bounds__(64) void k_feats(
    const float* __restrict__ h1,  // [2][2048][512]
    const float* __restrict__ Wt,  // [12][1024]
    const float* __restrict__ bt,  // [12]
    float* __restrict__ feats)     // [2048][12]
{
    int t = blockIdx.x;
    int lane = threadIdx.x;
    __shared__ __align__(16) float xl[1024];
    const float4* hf = (const float4*)(h1 + (size_t)t * 512);
    const float4* hb = (const float4*)(h1 + (size_t)(2048 + t) * 512);
    ((float4*)xl)[lane] = hf[lane];
    ((float4*)xl)[lane + 64] = hf[lane + 64];
    ((float4*)xl)[128 + lane] = hb[lane];
    ((float4*)xl)[128 + lane + 64] = hb[lane + 64];
    __syncthreads();
    for (int tag = 0; tag < NTAGS; ++tag) {
        const float* wrow = Wt + tag * 1024;
        float s = 0.f;
        for (int k = lane; k < 1024; k += 64) s += xl[k] * wrow[k];
#pragma unroll
        for (int off = 32; off; off >>= 1) s += __shfl_xor(s, off);
        if (lane == 0) feats[t * NTAGS + tag] = s + bt[tag];
    }
}

// ---------------------------------------------------------------------------
// K6: Viterbi forward + backtrack, single 64-thread block.
// Backpointers kept in LDS as uchar; feats prefetched in 256-step chunks.
// out[0] = path_score, out[1..2048] = best_path (as floats)
// ---------------------------------------------------------------------------
__global__ __launch_bounds__(64) void k_viterbi(
    const float* __restrict__ feats, const float* __restrict__ trans,
    float* __restrict__ out) {
    __shared__ float fv[2][NTAGS];
    __shared__ unsigned char bp[SEQ * NTAGS];  // 24 KB
    __shared__ float featbuf[256 * NTAGS];     // 12 KB
    __shared__ float term[NTAGS];
    int lane = threadIdx.x;

    float tr[NTAGS];
    if (lane < NTAGS) {
#pragma unroll
        for (int p = 0; p < NTAGS; ++p) tr[p] = trans[lane * NTAGS + p];
        fv[0][lane] = (lane == START_TAG) ? 0.f : NEGV;
    }
    __syncthreads();

    int cur = 0;
    for (int tc = 0; tc < SEQ; tc += 256) {
        for (int i = lane; i < 256 * NTAGS; i += 64) featbuf[i] = feats[tc * NTAGS + i];
        __syncthreads();
        for (int tt = 0; tt < 256; ++tt) {
            int t = tc + tt;
            if (lane < NTAGS) {
                float best = fv[cur][0] + tr[0];
                int bi = 0;
#pragma unroll
                for (int p = 1; p < NTAGS; ++p) {
                    float s = fv[cur][p] + tr[p];
                    if (s > best) { best = s; bi = p; }  // strict > keeps first max (jnp.argmax)
                }
                bp[t * NTAGS + lane] = (unsigned char)bi;
                fv[cur ^ 1][lane] = best + featbuf[tt * NTAGS + lane];
            }
            cur ^= 1;
            __syncthreads();
        }
    }

    if (lane < NTAGS) term[lane] = fv[cur][lane] + trans[STOP_TAG * NTAGS + lane];
    __syncthreads();
    if (lane == 0) {
        float best = term[0];
        int bi = 0;
        for (int p = 1; p < NTAGS; ++p) {
            if (term[p] > best) { best = term[p]; bi = p; }
        }
        out[0] = best;
        int tag = bi;
        out[1 + (SEQ - 1)] = (float)tag;
        for (int t = SEQ - 1; t >= 1; --t) {
            tag = bp[t * NTAGS + tag];
            out[t] = (float)tag;  // out[1+(t-1)]
        }
    }
}

// ---------------------------------------------------------------------------
extern "C" void kernel_launch(void* const* d_in, const int* in_sizes, int n_in,
                              void* d_out, int out_size, void* d_ws, size_t ws_size,
                              hipStream_t stream) {
    const int* sent = (const int*)d_in[0];
    const float* emb = (const float*)d_in[1];
    const float* Wih0 = (const float*)d_in[2];
    const float* Whh0 = (const float*)d_in[3];
    const float* bih0 = (const float*)d_in[4];
    const float* bhh0 = (const float*)d_in[5];
    const float* Wih1 = (const float*)d_in[6];
    const float* Whh1 = (const float*)d_in[7];
    const float* bih1 = (const float*)d_in[8];
    const float* bhh1 = (const float*)d_in[9];
    const float* Wtag = (const float*)d_in[10];
    const float* btag = (const float*)d_in[11];
    const float* trans = (const float*)d_in[12];
    float* out = (float*)d_out;

    char* ws = (char*)d_ws;
    size_t off = 0;
    auto alloc = [&](size_t bytes) {
        void* p = ws + off;
        off += (bytes + 255) & ~(size_t)255;
        return p;
    };
    float* x0 = (float*)alloc(2048ull * 512 * 4);          // 4 MB
    float* Gi = (float*)alloc(2ull * 2048 * 2048 * 4);     // 32 MB (reused layer0/1)
    float* h0 = (float*)alloc(2ull * 2048 * 512 * 4);      // 8 MB
    float* h1 = (float*)alloc(2ull * 2048 * 512 * 4);      // 8 MB
    float* feats = (float*)alloc(2048ull * NTAGS * 4);
    int* arr0 = (int*)alloc(2ull * 2048 * 4);
    int* arr1 = (int*)alloc(2ull * 2048 * 4);

    hipMemsetAsync(arr0, 0, 2ull * 2048 * 4, stream);
    hipMemsetAsync(arr1, 0, 2ull * 2048 * 4, stream);

    k_embed<<<2048, 128, 0, stream>>>(sent, emb, x0);

    dim3 gg(32, 32, 2);
    // layer 0 input gates: Gi = x0 @ Wih0^T + bih0 + bhh0  (K=512)
    k_gemm<<<gg, 256, 0, stream>>>(x0, x0, Wih0, bih0, bhh0, Gi, 512);
    // layer 0 recurrence
    k_lstm<<<64, 256, 0, stream>>>(Whh0, Gi, h0, arr0);
    // layer 1 input gates: Gi = concat(h0f,h0b) @ Wih1^T + b  (K=1024)
    k_gemm<<<gg, 256, 0, stream>>>(h0, h0 + 2048ull * 512, Wih1, bih1, bhh1, Gi, 1024);
    // layer 1 recurrence
    k_lstm<<<64, 256, 0, stream>>>(Whh1, Gi, h1, arr1);
    // tag projection
    k_feats<<<2048, 64, 0, stream>>>(h1, Wtag, btag, feats);
    // viterbi decode
    k_viterbi<<<1, 64, 0, stream>>>(feats, trans, out);
}

// Round 2
// 10210.883 us; speedup vs baseline: 2.0620x; 2.0620x over previous
//
#include <hip/hip_runtime.h>
#include <math.h>

// Problem constants
#define SEQ 2048
#define EMB_D 512
#define HID 512
#define NTAGS 12
#define START_TAG 10
#define STOP_TAG 11
#define NEGV (-10000.0f)
#define POISON 0xAAAAAAAAu

__device__ __forceinline__ float sigf(float x) { return 1.0f / (1.0f + expf(-x)); }

// ---------------------------------------------------------------------------
// K0: embedding gather  x0[t][e] = emb[sentence[t]][e]
// ---------------------------------------------------------------------------
__global__ void k_embed(const int* __restrict__ sent, const float* __restrict__ emb,
                        float* __restrict__ x0) {
    int t = blockIdx.x;
    int tid = threadIdx.x;  // 128 threads, 128 float4 = 512 floats
    int row = sent[t];
    const float4* src = (const float4*)(emb + (size_t)row * EMB_D);
    float4* dst = (float4*)(x0 + (size_t)t * EMB_D);
    dst[tid] = src[tid];
}

// ---------------------------------------------------------------------------
// K1/K3: fp32 GEMM  C[d][m][n] = sum_k A[m][k] * B[d][n][k] + biasA[d][n]+biasB[d][n]
// A[m][k] = (k<512 ? Af[m*512+k] : Ab[m*512+(k-512)])  (handles concat input)
// M = N = 2048 fixed, K in {512,1024}. Tile 64x64, BK=32, 256 threads, 4x4/thread.
// ---------------------------------------------------------------------------
#define BM 64
#define BN 64
#define BKT 32
#define LDT 68

__global__ __launch_bounds__(256) void k_gemm(
    const float* __restrict__ Af, const float* __restrict__ Ab,
    const float* __restrict__ B,
    const float* __restrict__ biasA, const float* __restrict__ biasB,
    float* __restrict__ C, int K) {
    const int N = 2048;
    int dir = blockIdx.z;
    const float* Bd = B + (size_t)dir * N * K;
    const float* bA = biasA + dir * N;
    const float* bB = biasB + dir * N;
    float* Cd = C + (size_t)dir * 2048 * N;
    int m0 = blockIdx.y * BM, n0 = blockIdx.x * BN;

    __shared__ float As[BKT * LDT];
    __shared__ float Bs[BKT * LDT];

    int tid = threadIdx.x;
    int lrow = tid >> 2;          // 0..63
    int lk4 = (tid & 3) * 8;      // 0,8,16,24
    int tx = tid & 15, ty = tid >> 4;

    float acc[4][4] = {};

    for (int kt = 0; kt < K; kt += BKT) {
        // load A tile (k-major in LDS)
        {
            int m = m0 + lrow;
#pragma unroll
            for (int hh = 0; hh < 2; ++hh) {
                int k = kt + lk4 + hh * 4;
                const float* src = (k < 512) ? (Af + (size_t)m * 512 + k)
                                             : (Ab + (size_t)m * 512 + (k - 512));
                float4 v = *(const float4*)src;
                int kl = lk4 + hh * 4;
                As[(kl + 0) * LDT + lrow] = v.x;
                As[(kl + 1) * LDT + lrow] = v.y;
                As[(kl + 2) * LDT + lrow] = v.z;
                As[(kl + 3) * LDT + lrow] = v.w;
            }
        }
        // load B tile
        {
            int n = n0 + lrow;
#pragma unroll
            for (int hh = 0; hh < 2; ++hh) {
                int k = kt + lk4 + hh * 4;
                float4 v = *(const float4*)(Bd + (size_t)n * K + k);
                int kl = lk4 + hh * 4;
                Bs[(kl + 0) * LDT + lrow] = v.x;
                Bs[(kl + 1) * LDT + lrow] = v.y;
                Bs[(kl + 2) * LDT + lrow] = v.z;
                Bs[(kl + 3) * LDT + lrow] = v.w;
            }
        }
        __syncthreads();
#pragma unroll
        for (int kk = 0; kk < BKT; ++kk) {
            float4 av = *(const float4*)&As[kk * LDT + ty * 4];
            float4 bv = *(const float4*)&Bs[kk * LDT + tx * 4];
            acc[0][0] += av.x * bv.x; acc[0][1] += av.x * bv.y; acc[0][2] += av.x * bv.z; acc[0][3] += av.x * bv.w;
            acc[1][0] += av.y * bv.x; acc[1][1] += av.y * bv.y; acc[1][2] += av.y * bv.z; acc[1][3] += av.y * bv.w;
            acc[2][0] += av.z * bv.x; acc[2][1] += av.z * bv.y; acc[2][2] += av.z * bv.z; acc[2][3] += av.z * bv.w;
            acc[3][0] += av.w * bv.x; acc[3][1] += av.w * bv.y; acc[3][2] += av.w * bv.z; acc[3][3] += av.w * bv.w;
        }
        __syncthreads();
    }
#pragma unroll
    for (int i = 0; i < 4; ++i) {
        int m = m0 + ty * 4 + i;
#pragma unroll
        for (int j = 0; j < 4; ++j) {
            int n = n0 + tx * 4 + j;
            Cd[(size_t)m * N + n] = acc[i][j] + bA[n] + bB[n];
        }
    }
}

// ---------------------------------------------------------------------------
// K2/K4: LSTM recurrence, one layer, both directions.
// 64 WGs (32 per direction), 256 threads each, persistent over 2048 steps.
// Each WG owns 16 hidden units (64 gate rows); Whh slice register-resident
// (128 floats/thread; __launch_bounds__(256,1) -> 512-VGPR budget so the
// compiler does NOT sink the weight loads into the loop).
// Cross-WG h broadcast: producers do relaxed agent-scope atomic stores
// (land at the coherent LLC); consumers poll the data words themselves
// (0xAA poison = "not yet written"), no fences, no counters.
// ---------------------------------------------------------------------------
__global__ __launch_bounds__(256, 1) void k_lstm(
    const float* __restrict__ Whh,  // [2][2048][512]
    const float* __restrict__ Gi,   // [2][2048][2048]  (Wih@x + bih + bhh)
    float* __restrict__ hstore)     // [2][2048][512], pre-poisoned 0xAA
{
    int wg = blockIdx.x;
    int dir = wg >> 5;
    int slice = wg & 31;
    int u_base = slice * 16;
    int tid = threadIdx.x;

    const float* Whh_d = Whh + (size_t)dir * 2048 * 512;
    const float* Gi_d = Gi + (size_t)dir * 2048 * 2048;
    float* h_d = hstore + (size_t)dir * 2048 * 512;

    int rl = tid >> 2;   // local gate row 0..63
    int kp = tid & 3;    // k-quarter
    int gg = rl >> 4;    // gate (i,f,g,o)
    int uu = rl & 15;    // unit offset 0..15
    int r = gg * 512 + u_base + uu;  // global gate-row in [0,2048)
    // (gg,uu) mapping makes kp==0 lanes' Gi addresses consecutive per gate.

    // weights into registers: w[j] = Whh[dir][r][kp*128 + j]
    float w[128];
    {
        const float* wsrc = Whh_d + (size_t)r * 512 + kp * 128;
#pragma unroll
        for (int j = 0; j < 128; j += 4) {
            float4 v = *(const float4*)(wsrc + j);
            w[j] = v.x; w[j + 1] = v.y; w[j + 2] = v.z; w[j + 3] = v.w;
        }
    }

    __shared__ __align__(16) float hlds[512];
    __shared__ float gdot[64];
    float c_reg = 0.0f;

    for (int it = 0; it < 2048; ++it) {
        int t = dir ? (2047 - it) : it;

        // Gi prefetch — independent of the recurrence, issue before the poll.
        float gi = 0.f;
        if (kp == 0) gi = Gi_d[(size_t)t * 2048 + r];

        if (it == 0) {
            ((float2*)hlds)[tid] = make_float2(0.f, 0.f);
        } else {
            int tprev = dir ? (t + 1) : (t - 1);
            const float* src = h_d + (size_t)tprev * 512 + 2 * tid;
            float a, b;
            do {
                a = __hip_atomic_load(src + 0, __ATOMIC_RELAXED, __HIP_MEMORY_SCOPE_AGENT);
                b = __hip_atomic_load(src + 1, __ATOMIC_RELAXED, __HIP_MEMORY_SCOPE_AGENT);
            } while (__float_as_uint(a) == POISON || __float_as_uint(b) == POISON);
            hlds[2 * tid] = a;
            hlds[2 * tid + 1] = b;
        }
        __syncthreads();

        // partial dot over this thread's k-quarter
        float p = 0.f;
        const float4* h4 = (const float4*)hlds + kp * 32;
#pragma unroll
        for (int j4 = 0; j4 < 32; ++j4) {
            float4 hv = h4[j4];
            p += w[4 * j4 + 0] * hv.x;
            p += w[4 * j4 + 1] * hv.y;
            p += w[4 * j4 + 2] * hv.z;
            p += w[4 * j4 + 3] * hv.w;
        }
        p += __shfl_xor(p, 1);
        p += __shfl_xor(p, 2);
        if (kp == 0) gdot[rl] = p + gi;
        __syncthreads();

        if (tid < 16) {
            float iv = gdot[0 * 16 + tid];
            float fv = gdot[1 * 16 + tid];
            float gv = gdot[2 * 16 + tid];
            float ov = gdot[3 * 16 + tid];
            float c = sigf(fv) * c_reg + sigf(iv) * tanhf(gv);
            float h = sigf(ov) * tanhf(c);
            c_reg = c;
            // publish at the coherent point; the value itself is the flag
            __hip_atomic_store(h_d + (size_t)t * 512 + u_base + tid, h,
                               __ATOMIC_RELAXED, __HIP_MEMORY_SCOPE_AGENT);
        }
        // no trailing barrier needed: next iteration's hlds/gdot writes are
        // separated from this iteration's reads by the two barriers above.
    }
}

// ---------------------------------------------------------------------------
// K5: feats[t][tag] = sum_k concat(h1f[t],h1b[t])[k] * W_tag[tag][k] + b_tag[tag]
// one 64-thread block per t
// ---------------------------------------------------------------------------
__global__ __launch_bounds__(64) void k_feats(
    const float* __restrict__ h1,  // [2][2048][512]
    const float* __restrict__ Wt,  // [12][1024]
    const float* __restrict__ bt,  // [12]
    float* __restrict__ feats)     // [2048][12]
{
    int t = blockIdx.x;
    int lane = threadIdx.x;
    __shared__ __align__(16) float xl[1024];
    const float4* hf = (const float4*)(h1 + (size_t)t * 512);
    const float4* hb = (const float4*)(h1 + (size_t)(2048 + t) * 512);
    ((float4*)xl)[lane] = hf[lane];
    ((float4*)xl)[lane + 64] = hf[lane + 64];
    ((float4*)xl)[128 + lane] = hb[lane];
    ((float4*)xl)[128 + lane + 64] = hb[lane + 64];
    __syncthreads();
    for (int tag = 0; tag < NTAGS; ++tag) {
        const float* wrow = Wt + tag * 1024;
        float s = 0.f;
        for (int k = lane; k < 1024; k += 64) s += xl[k] * wrow[k];
#pragma unroll
        for (int off = 32; off; off >>= 1) s += __shfl_xor(s, off);
        if (lane == 0) feats[t * NTAGS + tag] = s + bt[tag];
    }
}

// ---------------------------------------------------------------------------
// K6: Viterbi forward + backtrack, single 64-thread block.
// Backpointers kept in LDS as uchar; feats prefetched in 256-step chunks.
// out[0] = path_score, out[1..2048] = best_path (as floats)
// ---------------------------------------------------------------------------
__global__ __launch_bounds__(64) void k_viterbi(
    const float* __restrict__ feats, const float* __restrict__ trans,
    float* __restrict__ out) {
    __shared__ float fv[2][NTAGS];
    __shared__ unsigned char bp[SEQ * NTAGS];  // 24 KB
    __shared__ float featbuf[256 * NTAGS];     // 12 KB
    __shared__ float term[NTAGS];
    int lane = threadIdx.x;

    float tr[NTAGS];
    if (lane < NTAGS) {
#pragma unroll
        for (int p = 0; p < NTAGS; ++p) tr[p] = trans[lane * NTAGS + p];
        fv[0][lane] = (lane == START_TAG) ? 0.f : NEGV;
    }
    __syncthreads();

    int cur = 0;
    for (int tc = 0; tc < SEQ; tc += 256) {
        for (int i = lane; i < 256 * NTAGS; i += 64) featbuf[i] = feats[tc * NTAGS + i];
        __syncthreads();
        for (int tt = 0; tt < 256; ++tt) {
            int t = tc + tt;
            if (lane < NTAGS) {
                float best = fv[cur][0] + tr[0];
                int bi = 0;
#pragma unroll
                for (int p = 1; p < NTAGS; ++p) {
                    float s = fv[cur][p] + tr[p];
                    if (s > best) { best = s; bi = p; }  // strict > keeps first max (jnp.argmax)
                }
                bp[t * NTAGS + lane] = (unsigned char)bi;
                fv[cur ^ 1][lane] = best + featbuf[tt * NTAGS + lane];
            }
            cur ^= 1;
            __syncthreads();
        }
    }

    if (lane < NTAGS) term[lane] = fv[cur][lane] + trans[STOP_TAG * NTAGS + lane];
    __syncthreads();
    if (lane == 0) {
        float best = term[0];
        int bi = 0;
        for (int p = 1; p < NTAGS; ++p) {
            if (term[p] > best) { best = term[p]; bi = p; }
        }
        out[0] = best;
        int tag = bi;
        out[1 + (SEQ - 1)] = (float)tag;
        for (int t = SEQ - 1; t >= 1; --t) {
            tag = bp[t * NTAGS + tag];
            out[t] = (float)tag;  // out[1+(t-1)]
        }
    }
}

// ---------------------------------------------------------------------------
extern "C" void kernel_launch(void* const* d_in, const int* in_sizes, int n_in,
                              void* d_out, int out_size, void* d_ws, size_t ws_size,
                              hipStream_t stream) {
    const int* sent = (const int*)d_in[0];
    const float* emb = (const float*)d_in[1];
    const float* Wih0 = (const float*)d_in[2];
    const float* Whh0 = (const float*)d_in[3];
    const float* bih0 = (const float*)d_in[4];
    const float* bhh0 = (const float*)d_in[5];
    const float* Wih1 = (const float*)d_in[6];
    const float* Whh1 = (const float*)d_in[7];
    const float* bih1 = (const float*)d_in[8];
    const float* bhh1 = (const float*)d_in[9];
    const float* Wtag = (const float*)d_in[10];
    const float* btag = (const float*)d_in[11];
    const float* trans = (const float*)d_in[12];
    float* out = (float*)d_out;

    char* ws = (char*)d_ws;
    size_t off = 0;
    auto alloc = [&](size_t bytes) {
        void* p = ws + off;
        off += (bytes + 255) & ~(size_t)255;
        return p;
    };
    float* x0 = (float*)alloc(2048ull * 512 * 4);          // 4 MB
    float* Gi = (float*)alloc(2ull * 2048 * 2048 * 4);     // 32 MB (reused layer0/1)
    float* h0 = (float*)alloc(2ull * 2048 * 512 * 4);      // 8 MB
    float* h1 = (float*)alloc(2ull * 2048 * 512 * 4);      // 8 MB
    float* feats = (float*)alloc(2048ull * NTAGS * 4);

    // poison h buffers: "not yet written" sentinel for the data-polling sync
    hipMemsetAsync(h0, 0xAA, 2ull * 2048 * 512 * 4, stream);
    hipMemsetAsync(h1, 0xAA, 2ull * 2048 * 512 * 4, stream);

    k_embed<<<2048, 128, 0, stream>>>(sent, emb, x0);

    dim3 gg(32, 32, 2);
    // layer 0 input gates: Gi = x0 @ Wih0^T + bih0 + bhh0  (K=512)
    k_gemm<<<gg, 256, 0, stream>>>(x0, x0, Wih0, bih0, bhh0, Gi, 512);
    // layer 0 recurrence
    k_lstm<<<64, 256, 0, stream>>>(Whh0, Gi, h0);
    // layer 1 input gates: Gi = concat(h0f,h0b) @ Wih1^T + b  (K=1024)
    k_gemm<<<gg, 256, 0, stream>>>(h0, h0 + 2048ull * 512, Wih1, bih1, bhh1, Gi, 1024);
    // layer 1 recurrence
    k_lstm<<<64, 256, 0, stream>>>(Whh1, Gi, h1);
    // tag projection
    k_feats<<<2048, 64, 0, stream>>>(h1, Wtag, btag, feats);
    // viterbi decode
    k_viterbi<<<1, 64, 0, stream>>>(feats, trans, out);
}